// Round 1
// 147.514 us; speedup vs baseline: 1.0348x; 1.0348x over previous
//
#include <hip/hip_runtime.h>

#define N_NODES 10000
#define N_EDGES 320000
#define DIM_IN  512
#define DIM_HID 128
#define HC      256   // HEADS*GC
#define NEG_SLOPE 0.2f
#define SLOT    96    // fixed CSR stride; max degree+1 ~ 59 << 96 (11 sigma)

typedef short short8 __attribute__((ext_vector_type(8)));
typedef float floatx4 __attribute__((ext_vector_type(4)));

__device__ __forceinline__ unsigned short f2bf(float x) {  // RNE fp32->bf16
  unsigned int u = __float_as_uint(x);
  u += 0x7FFFu + ((u >> 16) & 1u);
  return (unsigned short)(u >> 16);
}

// ---------------------------------------------------------------------------
// fused1 (ONE launch, 640 blocks):
//   blocks 0..627  : gemm1 tile — h1b = bf16(relu(x @ W1 + b1)), bf16 MFMA,
//                    BM=64 BN=32 BK=32, 4 strips (R13 lesson: 628 light
//                    blocks beat 313 heavy ones). A staged fp32->bf16 from x
//                    directly; B staged from natural-layout W1 via in-LDS
//                    transpose (kills the xb conversion pass AND W1T).
//   blocks 628..639: prep GEMM [W2;b2]@Wg -> WfT bf16 [256][128] + bfuse
//                    + cursor zeroing (consumed by the NEXT launch only, so
//                    it can share this dispatch).
// ---------------------------------------------------------------------------
union Sm1 {
  struct { unsigned short As[64][48]; unsigned short Bs[32][48]; } g;  // 9216 B
  struct { float Ast[16][68]; float Bsf[16][64]; } p;                  // 8448 B
};

__global__ __launch_bounds__(256) void fused1_kernel(
    const float* __restrict__ x, const float* __restrict__ W1,
    const float* __restrict__ b1,
    const float* __restrict__ W2, const float* __restrict__ Wg,
    const float* __restrict__ b2,
    unsigned short* __restrict__ h1b, unsigned short* __restrict__ WfT,
    float* __restrict__ bfuse, int* __restrict__ cursor) {
  __shared__ Sm1 sm;
  const int t = threadIdx.x;
  const int b = blockIdx.x;

  if (b < 628) {
    constexpr int K = DIM_IN, N = DIM_HID, BK = 32;
    const int m0 = (b % 157) * 64, n0 = (b / 157) * 32;
    const int w = t >> 6, L = t & 63, lm = L & 15, q = L >> 4;
    floatx4 acc[2] = {};
    const int ar = t >> 3, ac = (t & 7) * 4;   // A rows ar/ar+32, k-off ac;
                                               // B k-row ar, n-off ac
    float4 va0, va1, vb, va0n, va1n, vbn;
    auto ld = [&](int kb, float4& a0, float4& a1, float4& bw) {
      a0 = (m0 + ar < N_NODES)
          ? *(const float4*)(x + (size_t)(m0 + ar) * K + kb + ac)
          : make_float4(0.f, 0.f, 0.f, 0.f);
      a1 = (m0 + ar + 32 < N_NODES)
          ? *(const float4*)(x + (size_t)(m0 + ar + 32) * K + kb + ac)
          : make_float4(0.f, 0.f, 0.f, 0.f);
      bw = *(const float4*)(W1 + (size_t)(kb + ar) * N + n0 + ac);
    };
    constexpr int NT = K / BK;  // 16
    ld(0, va0, va1, vb);
    for (int kt = 0; kt < NT; ++kt) {
      ushort4 s0 = {f2bf(va0.x), f2bf(va0.y), f2bf(va0.z), f2bf(va0.w)};
      ushort4 s1 = {f2bf(va1.x), f2bf(va1.y), f2bf(va1.z), f2bf(va1.w)};
      *(ushort4*)&sm.g.As[ar][ac]      = s0;
      *(ushort4*)&sm.g.As[ar + 32][ac] = s1;
      sm.g.Bs[ac + 0][ar] = f2bf(vb.x);   // in-LDS transpose of W1 tile
      sm.g.Bs[ac + 1][ar] = f2bf(vb.y);
      sm.g.Bs[ac + 2][ar] = f2bf(vb.z);
      sm.g.Bs[ac + 3][ar] = f2bf(vb.w);
      __syncthreads();
      if (kt + 1 < NT) ld((kt + 1) * BK, va0n, va1n, vbn);
      const short8 af = *(const short8*)&sm.g.As[w * 16 + lm][q * 8];
#pragma unroll
      for (int nt = 0; nt < 2; ++nt) {
        const short8 bf = *(const short8*)&sm.g.Bs[nt * 16 + lm][q * 8];
        acc[nt] = __builtin_amdgcn_mfma_f32_16x16x32_bf16(af, bf, acc[nt], 0, 0, 0);
      }
      __syncthreads();
      va0 = va0n; va1 = va1n; vb = vbn;
    }
    const int row0 = m0 + w * 16 + q * 4;
#pragma unroll
    for (int nt = 0; nt < 2; ++nt) {
      const int col = n0 + nt * 16 + lm;
      const float bv = b1[col];
#pragma unroll
      for (int r = 0; r < 4; ++r)
        if (row0 + r < N_NODES)
          h1b[(size_t)(row0 + r) * N + col] = f2bf(fmaxf(acc[nt][r] + bv, 0.f));
    }
    return;
  }

  // ----- prep blocks: [W2;b2]@Wg -> WfT + bfuse, and cursor zeroing -----
  const int bp = b - 628;  // 0..11
  {
    const int flat = bp * 256 + t;
    if (flat < (N_NODES + 3) / 4) ((int4*)cursor)[flat] = make_int4(0, 0, 0, 0);
  }
  const int bx = bp >> 2, by = bp & 3;
  const int tx = t & 15, ty = t >> 4;
  const int m0 = bx * 64, n0 = by * 64;
  const int ar = t >> 2, ac4 = (t & 3) * 4;
  const int br = t >> 4, bc4 = (t & 15) * 4;
  const int arow = m0 + ar;
  float acc[4][4] = {};
  float4 av, bv, avn, bvn;
  auto gload = [&](int k0, float4& a4, float4& b4) {
    if (arow < DIM_HID)       a4 = *(const float4*)(W2 + (size_t)arow * DIM_HID + k0 + ac4);
    else if (arow == DIM_HID) a4 = *(const float4*)(b2 + k0 + ac4);
    else                      a4 = make_float4(0.f, 0.f, 0.f, 0.f);
    b4 = *(const float4*)(Wg + (size_t)(k0 + br) * HC + n0 + bc4);
  };
  gload(0, av, bv);
  for (int k0 = 0; k0 < DIM_HID; k0 += 16) {
    sm.p.Ast[ac4 + 0][ar] = av.x; sm.p.Ast[ac4 + 1][ar] = av.y;
    sm.p.Ast[ac4 + 2][ar] = av.z; sm.p.Ast[ac4 + 3][ar] = av.w;
    *(float4*)&sm.p.Bsf[br][bc4] = bv;
    __syncthreads();
    if (k0 + 16 < DIM_HID) gload(k0 + 16, avn, bvn);
#pragma unroll
    for (int kk = 0; kk < 16; ++kk) {
      const float4 a = *(const float4*)&sm.p.Ast[kk][ty * 4];
      const float4 bq = *(const float4*)&sm.p.Bsf[kk][tx * 4];
      const float as[4] = {a.x, a.y, a.z, a.w};
      const float bs[4] = {bq.x, bq.y, bq.z, bq.w};
#pragma unroll
      for (int i = 0; i < 4; ++i)
#pragma unroll
        for (int j = 0; j < 4; ++j) acc[i][j] = fmaf(as[i], bs[j], acc[i][j]);
    }
    __syncthreads();
    av = avn; bv = bvn;
  }
#pragma unroll
  for (int i = 0; i < 4; ++i) {
    const int row = m0 + ty * 4 + i;
#pragma unroll
    for (int j = 0; j < 4; ++j) {
      const int col = n0 + tx * 4 + j;
      if (row < DIM_HID)       WfT[(size_t)col * DIM_HID + row] = f2bf(acc[i][j]);
      else if (row == DIM_HID) bfuse[col] = acc[i][j];
    }
  }
}

// ---------------------------------------------------------------------------
// gemm2: g = bf16(h1b @ Wfuse + bfuse), BM=BN=64 BK=32, ATT epilogue.
// Preamble: slot-96 CSR scatter (cursor zeroed in fused1's prep blocks).
// ---------------------------------------------------------------------------
__global__ __launch_bounds__(256) void gemm2_kernel(
    const unsigned short* __restrict__ h1b, const unsigned short* __restrict__ WfT,
    const float* __restrict__ bfuse, unsigned short* __restrict__ g,
    const float* __restrict__ att_src, const float* __restrict__ att_dst,
    float* __restrict__ a_src, float* __restrict__ a_dst,
    const int* __restrict__ e_src, const int* __restrict__ e_dst,
    int* __restrict__ cursor, int* __restrict__ src_sorted) {
  constexpr int K = DIM_HID, N = HC, BK = 32;
  __shared__ unsigned short As[64][48];
  __shared__ unsigned short Bs[64][48];
  const int t = threadIdx.x;
  {
    const int nthr = gridDim.x * gridDim.y * 256;
    const int flat = (blockIdx.y * gridDim.x + blockIdx.x) * 256 + t;
    for (int id = flat; id < N_EDGES + N_NODES; id += nthr) {
      int s, d;
      if (id < N_EDGES) { s = e_src[id]; d = e_dst[id]; }
      else              { s = d = id - N_EDGES; }
      src_sorted[d * SLOT + atomicAdd(&cursor[d], 1)] = s;
    }
  }
  const int m0 = blockIdx.x * 64, n0 = blockIdx.y * 64;
  const int w = t >> 6, L = t & 63, lm = L & 15, q = L >> 4;
  floatx4 acc[4] = {};
  uint4 ab, abn, bb, bbn;
  auto ld = [&](int kb, uint4& va, uint4& vb) {
    va = *(const uint4*)(h1b + (size_t)(m0 + (t >> 2)) * K + kb + (t & 3) * 8);
    vb = *(const uint4*)(WfT + (size_t)(n0 + (t >> 2)) * K + kb + (t & 3) * 8);
  };
  constexpr int NT = K / BK;  // 4
  ld(0, ab, bb);
  for (int kt = 0; kt < NT; ++kt) {
    *(uint4*)&As[t >> 2][(t & 3) * 8] = ab;
    *(uint4*)&Bs[t >> 2][(t & 3) * 8] = bb;
    __syncthreads();
    if (kt + 1 < NT) ld((kt + 1) * BK, abn, bbn);
    const short8 af = *(const short8*)&As[w * 16 + lm][q * 8];
#pragma unroll
    for (int nt = 0; nt < 4; ++nt) {
      const short8 bf = *(const short8*)&Bs[nt * 16 + lm][q * 8];
      acc[nt] = __builtin_amdgcn_mfma_f32_16x16x32_bf16(af, bf, acc[nt], 0, 0, 0);
    }
    __syncthreads();
    ab = abn; bb = bbn;
  }
  const int row0 = m0 + w * 16 + q * 4;
  const int hh = n0 >> 6;
  float ps[4] = {}, pd[4] = {};
#pragma unroll
  for (int nt = 0; nt < 4; ++nt) {
    const int col = n0 + nt * 16 + lm;
    const float bv = bfuse[col];
    const float as_c = att_src[hh * 64 + nt * 16 + lm];
    const float ad_c = att_dst[hh * 64 + nt * 16 + lm];
#pragma unroll
    for (int r = 0; r < 4; ++r) {
      const float gv = acc[nt][r] + bv;
      if (row0 + r < N_NODES) g[(size_t)(row0 + r) * N + col] = f2bf(gv);
      ps[r] = fmaf(gv, as_c, ps[r]);
      pd[r] = fmaf(gv, ad_c, pd[r]);
    }
  }
#pragma unroll
  for (int r = 0; r < 4; ++r) {
#pragma unroll
    for (int off = 1; off < 16; off <<= 1) {
      ps[r] += __shfl_xor(ps[r], off);
      pd[r] += __shfl_xor(pd[r], off);
    }
    if (lm == 0 && row0 + r < N_NODES) {
      a_src[(row0 + r) * 4 + hh] = ps[r];
      a_dst[(row0 + r) * 4 + hh] = pd[r];
    }
  }
}

// ---------------------------------------------------------------------------
// Aggregate v2: one wave per node (grid 2500*4 = exactly 10000 waves).
// Prologue builds a per-wave LDS table (sidx, w[4 heads]) for all edges of
// the node (exp/leaky-relu computed ONCE per edge, zero-padded to a multiple
// of 4 so the main loop needs no tail masking). Main loop: 4 edges x 16
// lanes, each lane owns 16 contiguous channels (one head): per iteration
// only 2 broadcast ds_reads + 2 dwordx4 row loads + 17 FMAs -- replaces the
// old 5-shfl-per-2-edges chain (DS ops/edge 2.5 -> 0.5, rows in flight 2->4).
// ---------------------------------------------------------------------------
__global__ __launch_bounds__(256) void aggregate_kernel(
    const unsigned short* __restrict__ g, const float* __restrict__ a_src,
    const float* __restrict__ a_dst, const int* __restrict__ cursor,
    const int* __restrict__ src_sorted, const float* __restrict__ bias_g,
    float* __restrict__ out) {
  __shared__ int   s_idx[4][SLOT];        // per-wave slices, no cross-wave use
  __shared__ float s_w[4][SLOT * 4];
  const int wv   = threadIdx.x >> 6;
  const int lane = threadIdx.x & 63;
  const int node = blockIdx.x * 4 + wv;   // grid = 2500, always < N_NODES
  const int start = node * SLOT;
  const int deg   = cursor[node];
  const int degp  = (deg + 3) & ~3;       // zero-padded edge count
  const float4 ad = *(const float4*)(a_dst + node * 4);

  // ---- build weight table (1 iter for deg<=64, which is always in practice)
  for (int j = lane; j < degp; j += 64) {
    int   s  = 0;
    float w0 = 0.f, w1 = 0.f, w2 = 0.f, w3 = 0.f;
    if (j < deg) {
      s = src_sorted[start + j];
      const float4 as4 = *(const float4*)(a_src + s * 4);
      float e0 = as4.x + ad.x; e0 = (e0 > 0.f) ? e0 : NEG_SLOPE * e0;
      float e1 = as4.y + ad.y; e1 = (e1 > 0.f) ? e1 : NEG_SLOPE * e1;
      float e2v = as4.z + ad.z; e2v = (e2v > 0.f) ? e2v : NEG_SLOPE * e2v;
      float e3 = as4.w + ad.w; e3 = (e3 > 0.f) ? e3 : NEG_SLOPE * e3;
      w0 = __expf(e0); w1 = __expf(e1); w2 = __expf(e2v); w3 = __expf(e3);
    }
    s_idx[wv][j] = s;
    float* wp = &s_w[wv][j * 4];
    wp[0] = w0; wp[1] = w1; wp[2] = w2; wp[3] = w3;
  }
  // All 256 threads alive (grid exactly covers N_NODES) -> barrier is safe;
  // it also guarantees the table writes are visible to the wave's own reads.
  __syncthreads();

  const int e4 = lane >> 4;     // edge sub-slot 0..3
  const int c4 = lane & 15;     // 16-channel block (one head: h = c4>>2)
  const int h  = c4 >> 2;
  const unsigned short* gbase = g + (size_t)c4 * 16;
  float a[16] = {};
  float s_loc = 0.f;
  const int iters = degp >> 2;
#pragma unroll 2
  for (int k = 0; k < iters; ++k) {
    const int j  = 4 * k + e4;
    const int sj = s_idx[wv][j];                 // 16-lane broadcast
    const float w = s_w[wv][j * 4 + h];          // 4-lane broadcast, padded->0
    const uint4 g0 = *(const uint4*)(gbase + (size_t)sj * HC);
    const uint4 g1 = *(const uint4*)(gbase + (size_t)sj * HC + 8);
    s_loc += w;
    a[0]  = fmaf(w, __uint_as_float(g0.x << 16),         a[0]);
    a[1]  = fmaf(w, __uint_as_float(g0.x & 0xFFFF0000u), a[1]);
    a[2]  = fmaf(w, __uint_as_float(g0.y << 16),         a[2]);
    a[3]  = fmaf(w, __uint_as_float(g0.y & 0xFFFF0000u), a[3]);
    a[4]  = fmaf(w, __uint_as_float(g0.z << 16),         a[4]);
    a[5]  = fmaf(w, __uint_as_float(g0.z & 0xFFFF0000u), a[5]);
    a[6]  = fmaf(w, __uint_as_float(g0.w << 16),         a[6]);
    a[7]  = fmaf(w, __uint_as_float(g0.w & 0xFFFF0000u), a[7]);
    a[8]  = fmaf(w, __uint_as_float(g1.x << 16),         a[8]);
    a[9]  = fmaf(w, __uint_as_float(g1.x & 0xFFFF0000u), a[9]);
    a[10] = fmaf(w, __uint_as_float(g1.y << 16),         a[10]);
    a[11] = fmaf(w, __uint_as_float(g1.y & 0xFFFF0000u), a[11]);
    a[12] = fmaf(w, __uint_as_float(g1.z << 16),         a[12]);
    a[13] = fmaf(w, __uint_as_float(g1.z & 0xFFFF0000u), a[13]);
    a[14] = fmaf(w, __uint_as_float(g1.w << 16),         a[14]);
    a[15] = fmaf(w, __uint_as_float(g1.w & 0xFFFF0000u), a[15]);
  }
  // reduce across the 4 edge sub-slots (lane bits 4 and 5)
#pragma unroll
  for (int k = 0; k < 16; ++k) {
    a[k] += __shfl_xor(a[k], 16);
    a[k] += __shfl_xor(a[k], 32);
  }
  s_loc += __shfl_xor(s_loc, 16);
  s_loc += __shfl_xor(s_loc, 32);
  if (e4 == 0) {
    const float inv = 1.f / s_loc;
    float* op = out + (size_t)node * HC + c4 * 16;
    const float* bp = bias_g + c4 * 16;
#pragma unroll
    for (int q = 0; q < 4; ++q) {
      const float4 bq = *(const float4*)(bp + q * 4);
      float4 o;
      o.x = a[4 * q + 0] * inv + bq.x;
      o.y = a[4 * q + 1] * inv + bq.y;
      o.z = a[4 * q + 2] * inv + bq.z;
      o.w = a[4 * q + 3] * inv + bq.w;
      *(float4*)(op + q * 4) = o;
    }
  }
}

// ---------------------------------------------------------------------------
extern "C" void kernel_launch(void* const* d_in, const int* in_sizes, int n_in,
                              void* d_out, int out_size, void* d_ws, size_t ws_size,
                              hipStream_t stream) {
  const float* x       = (const float*)d_in[0];
  const int*   ei      = (const int*)d_in[1];   // [2,E] int32: src then dst
  const float* W1      = (const float*)d_in[2];
  const float* b1      = (const float*)d_in[3];
  const float* W2      = (const float*)d_in[4];
  const float* b2      = (const float*)d_in[5];
  const float* Wg      = (const float*)d_in[6];
  const float* att_src = (const float*)d_in[7];
  const float* att_dst = (const float*)d_in[8];
  const float* bias_g  = (const float*)d_in[9];
  float* out = (float*)d_out;

  char* ws = (char*)d_ws;
  unsigned short* h1b = (unsigned short*)ws; ws += (size_t)(N_NODES + 64) * DIM_HID * 2;
  unsigned short* g   = (unsigned short*)ws; ws += (size_t)N_NODES * HC * 2;
  unsigned short* WfT = (unsigned short*)ws; ws += (size_t)HC * DIM_HID * 2;
  float* bfuse   = (float*)ws; ws += (size_t)HC * 4;
  float* a_src   = (float*)ws; ws += (size_t)N_NODES * 4 * 4;
  float* a_dst   = (float*)ws; ws += (size_t)N_NODES * 4 * 4;
  int* cursor    = (int*)ws;   ws += (size_t)N_NODES * 4;
  int* src_sorted= (int*)ws;   ws += (size_t)N_NODES * SLOT * 4;

  const dim3 blk(256);
  // 1. gemm1 (x + W1 staged from natural layouts) + prep GEMM + cursor zero
  fused1_kernel<<<640, blk, 0, stream>>>(
      x, W1, b1, W2, Wg, b2, h1b, WfT, bfuse, cursor);
  // 2. fused layer2+GAT MFMA -> bf16 g, attention epilogue, + slot-96 scatter
  gemm2_kernel<<<dim3(157, 4), blk, 0, stream>>>(
      h1b, WfT, bfuse, g, att_src, att_dst, a_src, a_dst,
      ei, ei + N_EDGES, cursor, src_sorted);
  // 3. segment softmax + weighted aggregate (wave per node, LDS weight table)
  aggregate_kernel<<<N_NODES / 4, blk, 0, stream>>>(
      g, a_src, a_dst, cursor, src_sorted, bias_g, out);
}

// Round 3
// 144.973 us; speedup vs baseline: 1.0530x; 1.0175x over previous
//
#include <hip/hip_runtime.h>

#define N_NODES 10000
#define N_EDGES 320000
#define DIM_IN  512
#define DIM_HID 128
#define HC      256   // HEADS*GC
#define NEG_SLOPE 0.2f
#define SLOT    96    // fixed CSR stride; max degree+1 ~ 59 << 96 (11 sigma)

typedef short short8 __attribute__((ext_vector_type(8)));
typedef float floatx4 __attribute__((ext_vector_type(4)));

__device__ __forceinline__ unsigned short f2bf(float x) {  // RNE fp32->bf16
  unsigned int u = __float_as_uint(x);
  u += 0x7FFFu + ((u >> 16) & 1u);
  return (unsigned short)(u >> 16);
}

// ---------------------------------------------------------------------------
// fused1 (ONE launch, 640 blocks):
//   blocks 0..627  : gemm1 tile — h1b = bf16(relu(x @ W1 + b1)), bf16 MFMA,
//                    BM=64 BN=32 BK=32, 4 strips. R3 changes:
//                    * LDS stride 48->40 u16 (80 B row = 20 dwords; b128
//                      fragment reads go 4-way-conflicted -> 2-way (free)).
//                    * W1 transpose writes XOR-swizzled on k-groups
//                      (physgrp = (k>>3) ^ ((n>>2)&3)): 8-way -> conflict-free.
//                    * double-buffered LDS: one barrier per K-step (was 2).
//   blocks 628..639: prep GEMM [W2;b2]@Wg -> WfT bf16 + bfuse + cursor zero.
// ---------------------------------------------------------------------------
union Sm1 {
  struct { unsigned short As[2][64][40]; unsigned short Bs[2][32][40]; } g;  // 15360 B
  struct { float Ast[16][68]; float Bsf[16][64]; } p;                        // 8448 B
};

__global__ __launch_bounds__(256) void fused1_kernel(
    const float* __restrict__ x, const float* __restrict__ W1,
    const float* __restrict__ b1,
    const float* __restrict__ W2, const float* __restrict__ Wg,
    const float* __restrict__ b2,
    unsigned short* __restrict__ h1b, unsigned short* __restrict__ WfT,
    float* __restrict__ bfuse, int* __restrict__ cursor) {
  __shared__ Sm1 sm;
  const int t = threadIdx.x;
  const int b = blockIdx.x;

  if (b < 628) {
    constexpr int K = DIM_IN, N = DIM_HID, BK = 32;
    const int m0 = (b % 157) * 64, n0 = (b / 157) * 32;
    const int w = t >> 6, L = t & 63, lm = L & 15, q = L >> 4;
    floatx4 acc[2] = {};
    const int ar = t >> 3, ac = (t & 7) * 4;   // A rows ar/ar+32, k-off ac;
                                               // B k-row ar, n-off ac
    // swizzled physical column for the 4 Bs transpose writes: for all i,
    // (n>>2)&3 == t&3 (since n = 4*(t&7)+i, i<4), so one bcol serves all 4.
    const int bcol = (ar & 7) | (((ar >> 3) ^ (t & 3)) << 3);
    float4 va0, va1, vb, va0n, va1n, vbn;
    auto ld = [&](int kb, float4& a0, float4& a1, float4& bw) {
      a0 = (m0 + ar < N_NODES)
          ? *(const float4*)(x + (size_t)(m0 + ar) * K + kb + ac)
          : make_float4(0.f, 0.f, 0.f, 0.f);
      a1 = (m0 + ar + 32 < N_NODES)
          ? *(const float4*)(x + (size_t)(m0 + ar + 32) * K + kb + ac)
          : make_float4(0.f, 0.f, 0.f, 0.f);
      bw = *(const float4*)(W1 + (size_t)(kb + ar) * N + n0 + ac);
    };
    constexpr int NT = K / BK;  // 16
    ld(0, va0, va1, vb);
    for (int kt = 0; kt < NT; ++kt) {
      const int p = kt & 1;
      ushort4 s0 = {f2bf(va0.x), f2bf(va0.y), f2bf(va0.z), f2bf(va0.w)};
      ushort4 s1 = {f2bf(va1.x), f2bf(va1.y), f2bf(va1.z), f2bf(va1.w)};
      *(ushort4*)&sm.g.As[p][ar][ac]      = s0;
      *(ushort4*)&sm.g.As[p][ar + 32][ac] = s1;
      sm.g.Bs[p][ac + 0][bcol] = f2bf(vb.x);   // in-LDS transpose of W1 tile
      sm.g.Bs[p][ac + 1][bcol] = f2bf(vb.y);   // (swizzled, conflict-free)
      sm.g.Bs[p][ac + 2][bcol] = f2bf(vb.z);
      sm.g.Bs[p][ac + 3][bcol] = f2bf(vb.w);
      __syncthreads();   // single barrier per step (double-buffered WAR-safe)
      if (kt + 1 < NT) ld((kt + 1) * BK, va0n, va1n, vbn);
      const short8 af = *(const short8*)&sm.g.As[p][w * 16 + lm][q * 8];
#pragma unroll
      for (int nt = 0; nt < 2; ++nt) {
        const int row = nt * 16 + lm;
        const int kg  = q ^ ((row >> 2) & 3);  // un-swizzle k-group
        const short8 bf = *(const short8*)&sm.g.Bs[p][row][kg * 8];
        acc[nt] = __builtin_amdgcn_mfma_f32_16x16x32_bf16(af, bf, acc[nt], 0, 0, 0);
      }
      va0 = va0n; va1 = va1n; vb = vbn;
    }
    const int row0 = m0 + w * 16 + q * 4;
#pragma unroll
    for (int nt = 0; nt < 2; ++nt) {
      const int col = n0 + nt * 16 + lm;
      const float bv = b1[col];
#pragma unroll
      for (int r = 0; r < 4; ++r)
        if (row0 + r < N_NODES)
          h1b[(size_t)(row0 + r) * N + col] = f2bf(fmaxf(acc[nt][r] + bv, 0.f));
    }
    return;
  }

  // ----- prep blocks: [W2;b2]@Wg -> WfT + bfuse, and cursor zeroing -----
  const int bp = b - 628;  // 0..11
  {
    const int flat = bp * 256 + t;
    if (flat < (N_NODES + 3) / 4) ((int4*)cursor)[flat] = make_int4(0, 0, 0, 0);
  }
  const int bx = bp >> 2, by = bp & 3;
  const int tx = t & 15, ty = t >> 4;
  const int m0 = bx * 64, n0 = by * 64;
  const int ar = t >> 2, ac4 = (t & 3) * 4;
  const int br = t >> 4, bc4 = (t & 15) * 4;
  const int arow = m0 + ar;
  float acc[4][4] = {};
  float4 av, bv, avn, bvn;
  auto gload = [&](int k0, float4& a4, float4& b4) {
    if (arow < DIM_HID)       a4 = *(const float4*)(W2 + (size_t)arow * DIM_HID + k0 + ac4);
    else if (arow == DIM_HID) a4 = *(const float4*)(b2 + k0 + ac4);
    else                      a4 = make_float4(0.f, 0.f, 0.f, 0.f);
    b4 = *(const float4*)(Wg + (size_t)(k0 + br) * HC + n0 + bc4);
  };
  gload(0, av, bv);
  for (int k0 = 0; k0 < DIM_HID; k0 += 16) {
    sm.p.Ast[ac4 + 0][ar] = av.x; sm.p.Ast[ac4 + 1][ar] = av.y;
    sm.p.Ast[ac4 + 2][ar] = av.z; sm.p.Ast[ac4 + 3][ar] = av.w;
    *(float4*)&sm.p.Bsf[br][bc4] = bv;
    __syncthreads();
    if (k0 + 16 < DIM_HID) gload(k0 + 16, avn, bvn);
#pragma unroll
    for (int kk = 0; kk < 16; ++kk) {
      const float4 a = *(const float4*)&sm.p.Ast[kk][ty * 4];
      const float4 bq = *(const float4*)&sm.p.Bsf[kk][tx * 4];
      const float as[4] = {a.x, a.y, a.z, a.w};
      const float bs[4] = {bq.x, bq.y, bq.z, bq.w};
#pragma unroll
      for (int i = 0; i < 4; ++i)
#pragma unroll
        for (int j = 0; j < 4; ++j) acc[i][j] = fmaf(as[i], bs[j], acc[i][j]);
    }
    __syncthreads();
    av = avn; bv = bvn;
  }
#pragma unroll
  for (int i = 0; i < 4; ++i) {
    const int row = m0 + ty * 4 + i;
#pragma unroll
    for (int j = 0; j < 4; ++j) {
      const int col = n0 + tx * 4 + j;
      if (row < DIM_HID)       WfT[(size_t)col * DIM_HID + row] = f2bf(acc[i][j]);
      else if (row == DIM_HID) bfuse[col] = acc[i][j];
    }
  }
}

// ---------------------------------------------------------------------------
// gemm2: g = bf16(h1b @ Wfuse + bfuse), BM=BN=64 BK=32, ATT epilogue.
// R3: stride 48->40 (fragment reads conflict-free) + double-buffered LDS
// (one barrier per K-step). Preamble: slot-96 CSR scatter.
// ---------------------------------------------------------------------------
__global__ __launch_bounds__(256) void gemm2_kernel(
    const unsigned short* __restrict__ h1b, const unsigned short* __restrict__ WfT,
    const float* __restrict__ bfuse, unsigned short* __restrict__ g,
    const float* __restrict__ att_src, const float* __restrict__ att_dst,
    float* __restrict__ a_src, float* __restrict__ a_dst,
    const int* __restrict__ e_src, const int* __restrict__ e_dst,
    int* __restrict__ cursor, int* __restrict__ src_sorted) {
  constexpr int K = DIM_HID, N = HC, BK = 32;
  __shared__ unsigned short As[2][64][40];
  __shared__ unsigned short Bs[2][64][40];
  const int t = threadIdx.x;
  {
    const int nthr = gridDim.x * gridDim.y * 256;
    const int flat = (blockIdx.y * gridDim.x + blockIdx.x) * 256 + t;
    for (int id = flat; id < N_EDGES + N_NODES; id += nthr) {
      int s, d;
      if (id < N_EDGES) { s = e_src[id]; d = e_dst[id]; }
      else              { s = d = id - N_EDGES; }
      src_sorted[d * SLOT + atomicAdd(&cursor[d], 1)] = s;
    }
  }
  const int m0 = blockIdx.x * 64, n0 = blockIdx.y * 64;
  const int w = t >> 6, L = t & 63, lm = L & 15, q = L >> 4;
  floatx4 acc[4] = {};
  uint4 ab, abn, bb, bbn;
  auto ld = [&](int kb, uint4& va, uint4& vb) {
    va = *(const uint4*)(h1b + (size_t)(m0 + (t >> 2)) * K + kb + (t & 3) * 8);
    vb = *(const uint4*)(WfT + (size_t)(n0 + (t >> 2)) * K + kb + (t & 3) * 8);
  };
  constexpr int NT = K / BK;  // 4
  ld(0, ab, bb);
  for (int kt = 0; kt < NT; ++kt) {
    const int p = kt & 1;
    *(uint4*)&As[p][t >> 2][(t & 3) * 8] = ab;
    *(uint4*)&Bs[p][t >> 2][(t & 3) * 8] = bb;
    __syncthreads();   // single barrier per step (double-buffered WAR-safe)
    if (kt + 1 < NT) ld((kt + 1) * BK, abn, bbn);
    const short8 af = *(const short8*)&As[p][w * 16 + lm][q * 8];
#pragma unroll
    for (int nt = 0; nt < 4; ++nt) {
      const short8 bf = *(const short8*)&Bs[p][nt * 16 + lm][q * 8];
      acc[nt] = __builtin_amdgcn_mfma_f32_16x16x32_bf16(af, bf, acc[nt], 0, 0, 0);
    }
    ab = abn; bb = bbn;
  }
  const int row0 = m0 + w * 16 + q * 4;
  const int hh = n0 >> 6;
  float ps[4] = {}, pd[4] = {};
#pragma unroll
  for (int nt = 0; nt < 4; ++nt) {
    const int col = n0 + nt * 16 + lm;
    const float bv = bfuse[col];
    const float as_c = att_src[hh * 64 + nt * 16 + lm];
    const float ad_c = att_dst[hh * 64 + nt * 16 + lm];
#pragma unroll
    for (int r = 0; r < 4; ++r) {
      const float gv = acc[nt][r] + bv;
      if (row0 + r < N_NODES) g[(size_t)(row0 + r) * N + col] = f2bf(gv);
      ps[r] = fmaf(gv, as_c, ps[r]);
      pd[r] = fmaf(gv, ad_c, pd[r]);
    }
  }
#pragma unroll
  for (int r = 0; r < 4; ++r) {
#pragma unroll
    for (int off = 1; off < 16; off <<= 1) {
      ps[r] += __shfl_xor(ps[r], off);
      pd[r] += __shfl_xor(pd[r], off);
    }
    if (lm == 0 && row0 + r < N_NODES) {
      a_src[(row0 + r) * 4 + hh] = ps[r];
      a_dst[(row0 + r) * 4 + hh] = pd[r];
    }
  }
}

// ---------------------------------------------------------------------------
// Aggregate (R1 proven): one wave per node, per-wave LDS weight table,
// 4 edges x 16 lanes main loop.
// ---------------------------------------------------------------------------
__global__ __launch_bounds__(256) void aggregate_kernel(
    const unsigned short* __restrict__ g, const float* __restrict__ a_src,
    const float* __restrict__ a_dst, const int* __restrict__ cursor,
    const int* __restrict__ src_sorted, const float* __restrict__ bias_g,
    float* __restrict__ out) {
  __shared__ int   s_idx[4][SLOT];        // per-wave slices, no cross-wave use
  __shared__ float s_w[4][SLOT * 4];
  const int wv   = threadIdx.x >> 6;
  const int lane = threadIdx.x & 63;
  const int node = blockIdx.x * 4 + wv;   // grid = 2500, always < N_NODES
  const int start = node * SLOT;
  const int deg   = cursor[node];
  const int degp  = (deg + 3) & ~3;       // zero-padded edge count
  const float4 ad = *(const float4*)(a_dst + node * 4);

  // ---- build weight table (1 iter for deg<=64, which is always in practice)
  for (int j = lane; j < degp; j += 64) {
    int    s  = 0;
    float4 wq = make_float4(0.f, 0.f, 0.f, 0.f);
    if (j < deg) {
      s = src_sorted[start + j];
      const float4 as4 = *(const float4*)(a_src + s * 4);
      float e0 = as4.x + ad.x; e0 = (e0 > 0.f) ? e0 : NEG_SLOPE * e0;
      float e1 = as4.y + ad.y; e1 = (e1 > 0.f) ? e1 : NEG_SLOPE * e1;
      float e2v = as4.z + ad.z; e2v = (e2v > 0.f) ? e2v : NEG_SLOPE * e2v;
      float e3 = as4.w + ad.w; e3 = (e3 > 0.f) ? e3 : NEG_SLOPE * e3;
      wq = make_float4(__expf(e0), __expf(e1), __expf(e2v), __expf(e3));
    }
    s_idx[wv][j] = s;
    *(float4*)&s_w[wv][j * 4] = wq;
  }
  // All 256 threads alive (grid exactly covers N_NODES) -> barrier is safe;
  // it also guarantees the table writes are visible to the wave's own reads.
  __syncthreads();

  const int e4 = lane >> 4;     // edge sub-slot 0..3
  const int c4 = lane & 15;     // 16-channel block (one head: h = c4>>2)
  const int h  = c4 >> 2;
  const unsigned short* gbase = g + (size_t)c4 * 16;
  float a[16] = {};
  float s_loc = 0.f;
  const int iters = degp >> 2;
#pragma unroll 2
  for (int k = 0; k < iters; ++k) {
    const int j  = 4 * k + e4;
    const int sj = s_idx[wv][j];                 // 16-lane broadcast
    const float w = s_w[wv][j * 4 + h];          // 4-lane broadcast, padded->0
    const uint4 g0 = *(const uint4*)(gbase + (size_t)sj * HC);
    const uint4 g1 = *(const uint4*)(gbase + (size_t)sj * HC + 8);
    s_loc += w;
    a[0]  = fmaf(w, __uint_as_float(g0.x << 16),         a[0]);
    a[1]  = fmaf(w, __uint_as_float(g0.x & 0xFFFF0000u), a[1]);
    a[2]  = fmaf(w, __uint_as_float(g0.y << 16),         a[2]);
    a[3]  = fmaf(w, __uint_as_float(g0.y & 0xFFFF0000u), a[3]);
    a[4]  = fmaf(w, __uint_as_float(g0.z << 16),         a[4]);
    a[5]  = fmaf(w, __uint_as_float(g0.z & 0xFFFF0000u), a[5]);
    a[6]  = fmaf(w, __uint_as_float(g0.w << 16),         a[6]);
    a[7]  = fmaf(w, __uint_as_float(g0.w & 0xFFFF0000u), a[7]);
    a[8]  = fmaf(w, __uint_as_float(g1.x << 16),         a[8]);
    a[9]  = fmaf(w, __uint_as_float(g1.x & 0xFFFF0000u), a[9]);
    a[10] = fmaf(w, __uint_as_float(g1.y << 16),         a[10]);
    a[11] = fmaf(w, __uint_as_float(g1.y & 0xFFFF0000u), a[11]);
    a[12] = fmaf(w, __uint_as_float(g1.z << 16),         a[12]);
    a[13] = fmaf(w, __uint_as_float(g1.z & 0xFFFF0000u), a[13]);
    a[14] = fmaf(w, __uint_as_float(g1.w << 16),         a[14]);
    a[15] = fmaf(w, __uint_as_float(g1.w & 0xFFFF0000u), a[15]);
  }
  // reduce across the 4 edge sub-slots (lane bits 4 and 5)
#pragma unroll
  for (int k = 0; k < 16; ++k) {
    a[k] += __shfl_xor(a[k], 16);
    a[k] += __shfl_xor(a[k], 32);
  }
  s_loc += __shfl_xor(s_loc, 16);
  s_loc += __shfl_xor(s_loc, 32);
  if (e4 == 0) {
    const float inv = 1.f / s_loc;
    float* op = out + (size_t)node * HC + c4 * 16;
    const float* bp = bias_g + c4 * 16;
#pragma unroll
    for (int q = 0; q < 4; ++q) {
      const float4 bq = *(const float4*)(bp + q * 4);
      float4 o;
      o.x = a[4 * q + 0] * inv + bq.x;
      o.y = a[4 * q + 1] * inv + bq.y;
      o.z = a[4 * q + 2] * inv + bq.z;
      o.w = a[4 * q + 3] * inv + bq.w;
      *(float4*)(op + q * 4) = o;
    }
  }
}

// ---------------------------------------------------------------------------
extern "C" void kernel_launch(void* const* d_in, const int* in_sizes, int n_in,
                              void* d_out, int out_size, void* d_ws, size_t ws_size,
                              hipStream_t stream) {
  const float* x       = (const float*)d_in[0];
  const int*   ei      = (const int*)d_in[1];   // [2,E] int32: src then dst
  const float* W1      = (const float*)d_in[2];
  const float* b1      = (const float*)d_in[3];
  const float* W2      = (const float*)d_in[4];
  const float* b2      = (const float*)d_in[5];
  const float* Wg      = (const float*)d_in[6];
  const float* att_src = (const float*)d_in[7];
  const float* att_dst = (const float*)d_in[8];
  const float* bias_g  = (const float*)d_in[9];
  float* out = (float*)d_out;

  char* ws = (char*)d_ws;
  unsigned short* h1b = (unsigned short*)ws; ws += (size_t)(N_NODES + 64) * DIM_HID * 2;
  unsigned short* g   = (unsigned short*)ws; ws += (size_t)N_NODES * HC * 2;
  unsigned short* WfT = (unsigned short*)ws; ws += (size_t)HC * DIM_HID * 2;
  float* bfuse   = (float*)ws; ws += (size_t)HC * 4;
  float* a_src   = (float*)ws; ws += (size_t)N_NODES * 4 * 4;
  float* a_dst   = (float*)ws; ws += (size_t)N_NODES * 4 * 4;
  int* cursor    = (int*)ws;   ws += (size_t)N_NODES * 4;
  int* src_sorted= (int*)ws;   ws += (size_t)N_NODES * SLOT * 4;

  const dim3 blk(256);
  // 1. gemm1 (x + W1 staged from natural layouts) + prep GEMM + cursor zero
  fused1_kernel<<<640, blk, 0, stream>>>(
      x, W1, b1, W2, Wg, b2, h1b, WfT, bfuse, cursor);
  // 2. fused layer2+GAT MFMA -> bf16 g, attention epilogue, + slot-96 scatter
  gemm2_kernel<<<dim3(157, 4), blk, 0, stream>>>(
      h1b, WfT, bfuse, g, att_src, att_dst, a_src, a_dst,
      ei, ei + N_EDGES, cursor, src_sorted);
  // 3. segment softmax + weighted aggregate (wave per node, LDS weight table)
  aggregate_kernel<<<(N_NODES + 3) / 4, blk, 0, stream>>>(
      g, a_src, a_dst, cursor, src_sorted, bias_g, out);
}